// Round 1
// baseline (47.651 us; speedup 1.0000x reference)
//
#include <hip/hip_runtime.h>
#include <stdint.h>

// ---------------------------------------------------------------------------
// SpecAugment: out[b,d,t] = x[b,d,t] * keep[b,d,t]
// keep derived from jax.random.key(42) via threefry2x32 — replicated bit-exact.
// Set JAX_PARTITIONABLE=0 if the harness JAX predates partitionable default.
// ---------------------------------------------------------------------------
#define JAX_PARTITIONABLE 1

#define BB 64
#define DD 128
#define TT 4000
#define NT4 1000   // TT/4

__device__ __forceinline__ uint32_t rotl32(uint32_t v, int r) {
  return (v << r) | (v >> (32 - r));
}

// Standard Threefry-2x32, 20 rounds, as in jax/_src/prng.py
__device__ __forceinline__ void threefry2x32(uint32_t k0, uint32_t k1,
                                             uint32_t x0, uint32_t x1,
                                             uint32_t& o0, uint32_t& o1) {
  const uint32_t ks2 = k0 ^ k1 ^ 0x1BD11BDAu;
  x0 += k0; x1 += k1;
#define TF_R(r) { x0 += x1; x1 = rotl32(x1, r); x1 ^= x0; }
  TF_R(13) TF_R(15) TF_R(26) TF_R(6)
  x0 += k1;  x1 += ks2 + 1u;
  TF_R(17) TF_R(29) TF_R(16) TF_R(24)
  x0 += ks2; x1 += k0 + 2u;
  TF_R(13) TF_R(15) TF_R(26) TF_R(6)
  x0 += k0;  x1 += k1 + 3u;
  TF_R(17) TF_R(29) TF_R(16) TF_R(24)
  x0 += k1;  x1 += ks2 + 4u;
  TF_R(13) TF_R(15) TF_R(26) TF_R(6)
  x0 += ks2; x1 += k0 + 5u;
#undef TF_R
  o0 = x0; o1 = x1;
}

// random_bits(key, 32, shape)[j]; n = prod(shape) (needed only in original mode)
__device__ __forceinline__ uint32_t jax_bits32(uint32_t ka, uint32_t kb,
                                               uint32_t j, uint32_t n) {
#if JAX_PARTITIONABLE
  (void)n;
  uint32_t a, b;
  threefry2x32(ka, kb, 0u, j, a, b);   // counter = uint64 j -> (hi=0, lo=j)
  return a ^ b;                        // 32-bit width: xor of both outputs
#else
  uint32_t half = n >> 1, a, b;
  if (j < half) { threefry2x32(ka, kb, j, j + half, a, b); return a; }
  threefry2x32(ka, kb, j - half, j, a, b); return b;
#endif
}

// i-th key of jax.random.split(key(42), 4)
__device__ __forceinline__ void jax_subkey42(int i, uint32_t& oa, uint32_t& ob) {
#if JAX_PARTITIONABLE
  threefry2x32(0u, 42u, 0u, (uint32_t)i, oa, ob);   // fold-like split
#else
  // original split: counts=iota(8), pairs (p, p+4); flat=[a0..a3,b0..b3]; reshape(4,2)
  uint32_t a[4], b[4];
  for (int p = 0; p < 4; ++p) threefry2x32(0u, 42u, (uint32_t)p, (uint32_t)(p + 4), a[p], b[p]);
  if      (i == 0) { oa = a[0]; ob = a[1]; }
  else if (i == 1) { oa = a[2]; ob = a[3]; }
  else if (i == 2) { oa = b[0]; ob = b[1]; }
  else             { oa = b[2]; ob = b[3]; }
#endif
}

// jax.random.randint(key, shape, 0, span)[flat j]; mult = 2^32 % span; n = prod(shape)
__device__ __forceinline__ uint32_t jax_randint0(uint32_t ka, uint32_t kb, uint32_t j,
                                                 uint32_t span, uint32_t mult, uint32_t n) {
  uint32_t k1a, k1b, k2a, k2b;
#if JAX_PARTITIONABLE
  threefry2x32(ka, kb, 0u, 0u, k1a, k1b);   // _split(key)[0]
  threefry2x32(ka, kb, 0u, 1u, k2a, k2b);   // _split(key)[1]
#else
  // original _split(key,2): p0=tf(key,(0,2)), p1=tf(key,(1,3)); k1=(p0.a,p1.a), k2=(p0.b,p1.b)
  uint32_t p0a, p0b, p1a, p1b;
  threefry2x32(ka, kb, 0u, 2u, p0a, p0b);
  threefry2x32(ka, kb, 1u, 3u, p1a, p1b);
  k1a = p0a; k1b = p1a; k2a = p0b; k2b = p1b;
#endif
  uint32_t hb = jax_bits32(k1a, k1b, j, n);
  uint32_t lb = jax_bits32(k2a, k2b, j, n);
  // ((hi % s) * (2^32 % s) + (lo % s)) % s  — no uint32 overflow for span<=102
  return ((hb % span) * mult + (lb % span)) % span;
}

__global__ __launch_bounds__(256) void specaug_kernel(
    const float* __restrict__ x, const int* __restrict__ len,
    float* __restrict__ out) {
  __shared__ int s_fs[2], s_fw[2], s_ts[10], s_tw[10];
  const int b   = blockIdx.y;
  const int tid = threadIdx.x;

  if (tid < 24) {
    if (tid < 2) {                       // f_start: randint(kf1,(64,2),0,102)
      uint32_t ka, kb; jax_subkey42(0, ka, kb);
      s_fs[tid] = (int)jax_randint0(ka, kb, (uint32_t)(b * 2 + tid), 102u, 52u, 128u);
    } else if (tid < 4) {                // f_w: randint(kf2,(64,2),0,28)
      int m = tid - 2;
      uint32_t ka, kb; jax_subkey42(1, ka, kb);
      s_fw[m] = (int)jax_randint0(ka, kb, (uint32_t)(b * 2 + m), 28u, 4u, 128u);
    } else if (tid < 14) {               // t_start: floor(uniform(kt1,(64,10)) * max_start)
      int m = tid - 4;
      uint32_t ka, kb; jax_subkey42(2, ka, kb);
      uint32_t bits = jax_bits32(ka, kb, (uint32_t)(b * 10 + m), 640u);
      float u = __uint_as_float((bits >> 9) | 0x3F800000u) - 1.0f;  // [0,1)
      int ms = len[b] - 99; if (ms < 1) ms = 1;                     // max(length-TW+1, 1)
      s_ts[m] = (int)floorf(u * (float)ms);
    } else {                             // t_w: randint(kt2,(64,10),0,101)
      int m = tid - 14;
      uint32_t ka, kb; jax_subkey42(3, ka, kb);
      s_tw[m] = (int)jax_randint0(ka, kb, (uint32_t)(b * 10 + m), 101u, 68u, 640u);
    }
  }
  __syncthreads();

  const int t4 = blockIdx.x * 256 + tid;   // float4 index within row
  if (t4 >= NT4) return;                   // no further barriers -> safe early-exit
  const int t0 = t4 * 4;

  // per-component time-keep multiplier (0.0 where any time mask hits)
  float m0 = 1.f, m1 = 1.f, m2 = 1.f, m3 = 1.f;
#pragma unroll
  for (int m = 0; m < 10; ++m) {
    int ts = s_ts[m], te = ts + s_tw[m];
    if (t0     >= ts && t0     < te) m0 = 0.f;
    if (t0 + 1 >= ts && t0 + 1 < te) m1 = 0.f;
    if (t0 + 2 >= ts && t0 + 2 < te) m2 = 0.f;
    if (t0 + 3 >= ts && t0 + 3 < te) m3 = 0.f;
  }

  const int d0 = blockIdx.z * 16;
  const float4* __restrict__ x4 = reinterpret_cast<const float4*>(x);
  float4* __restrict__ o4       = reinterpret_cast<float4*>(out);
  int64_t idx = (int64_t)(b * DD + d0) * NT4 + t4;

  for (int d = d0; d < d0 + 16; ++d, idx += NT4) {
    // block-uniform branch: d and s_fs/s_fw identical across the block
    bool fh = (d >= s_fs[0] && d < s_fs[0] + s_fw[0]) ||
              (d >= s_fs[1] && d < s_fs[1] + s_fw[1]);
    if (fh) {
      o4[idx] = make_float4(0.f, 0.f, 0.f, 0.f);   // skip the read entirely
    } else {
      float4 v = x4[idx];
      v.x *= m0; v.y *= m1; v.z *= m2; v.w *= m3;
      o4[idx] = v;
    }
  }
}

extern "C" void kernel_launch(void* const* d_in, const int* in_sizes, int n_in,
                              void* d_out, int out_size, void* d_ws, size_t ws_size,
                              hipStream_t stream) {
  (void)in_sizes; (void)n_in; (void)d_ws; (void)ws_size; (void)out_size;
  const float* x  = (const float*)d_in[0];
  const int* len  = (const int*)d_in[1];
  float* out      = (float*)d_out;
  dim3 grid(4 /* ceil(NT4/256) */, BB, DD / 16);
  dim3 block(256);
  hipLaunchKernelGGL(specaug_kernel, grid, block, 0, stream, x, len, out);
}

// Round 3
// 41.993 us; speedup vs baseline: 1.1347x; 1.1347x over previous
//
#include <hip/hip_runtime.h>
#include <stdint.h>

// ---------------------------------------------------------------------------
// SpecAugment: out[b,d,t] = x[b,d,t] * keep[b,d,t]
// keep derived from jax.random.key(42) via threefry2x32 — replicated bit-exact
// (partitionable mode, verified absmax=0 in R1).
// R3: R2 retry — nontemporal stores via ext_vector_type (clang builtin needs
// native vector, not HIP_vector_type) + d-loop unroll x4 for MLP.
// ---------------------------------------------------------------------------
#define BB 64
#define DD 128
#define TT 4000
#define NT4 1000   // TT/4

typedef float f32x4 __attribute__((ext_vector_type(4)));

__device__ __forceinline__ uint32_t rotl32(uint32_t v, int r) {
  return (v << r) | (v >> (32 - r));
}

// Standard Threefry-2x32, 20 rounds, as in jax/_src/prng.py
__device__ __forceinline__ void threefry2x32(uint32_t k0, uint32_t k1,
                                             uint32_t x0, uint32_t x1,
                                             uint32_t& o0, uint32_t& o1) {
  const uint32_t ks2 = k0 ^ k1 ^ 0x1BD11BDAu;
  x0 += k0; x1 += k1;
#define TF_R(r) { x0 += x1; x1 = rotl32(x1, r); x1 ^= x0; }
  TF_R(13) TF_R(15) TF_R(26) TF_R(6)
  x0 += k1;  x1 += ks2 + 1u;
  TF_R(17) TF_R(29) TF_R(16) TF_R(24)
  x0 += ks2; x1 += k0 + 2u;
  TF_R(13) TF_R(15) TF_R(26) TF_R(6)
  x0 += k0;  x1 += k1 + 3u;
  TF_R(17) TF_R(29) TF_R(16) TF_R(24)
  x0 += k1;  x1 += ks2 + 4u;
  TF_R(13) TF_R(15) TF_R(26) TF_R(6)
  x0 += ks2; x1 += k0 + 5u;
#undef TF_R
  o0 = x0; o1 = x1;
}

// random_bits(key, 32, shape)[j] — partitionable mode
__device__ __forceinline__ uint32_t jax_bits32(uint32_t ka, uint32_t kb, uint32_t j) {
  uint32_t a, b;
  threefry2x32(ka, kb, 0u, j, a, b);   // counter = uint64 j -> (hi=0, lo=j)
  return a ^ b;                        // 32-bit width: xor of both halves
}

// i-th key of jax.random.split(key(42), 4) — fold-like split
__device__ __forceinline__ void jax_subkey42(int i, uint32_t& oa, uint32_t& ob) {
  threefry2x32(0u, 42u, 0u, (uint32_t)i, oa, ob);
}

// jax.random.randint(key, shape, 0, span)[flat j]; mult = 2^32 % span
__device__ __forceinline__ uint32_t jax_randint0(uint32_t ka, uint32_t kb, uint32_t j,
                                                 uint32_t span, uint32_t mult) {
  uint32_t k1a, k1b, k2a, k2b;
  threefry2x32(ka, kb, 0u, 0u, k1a, k1b);   // _split(key)[0]
  threefry2x32(ka, kb, 0u, 1u, k2a, k2b);   // _split(key)[1]
  uint32_t hb = jax_bits32(k1a, k1b, j);
  uint32_t lb = jax_bits32(k2a, k2b, j);
  // ((hi % s) * (2^32 % s) + (lo % s)) % s  — no uint32 overflow for span<=102
  return ((hb % span) * mult + (lb % span)) % span;
}

__global__ __launch_bounds__(256) void specaug_kernel(
    const float* __restrict__ x, const int* __restrict__ len,
    float* __restrict__ out) {
  __shared__ int s_fs[2], s_fw[2], s_ts[10], s_tw[10];
  const int b   = blockIdx.y;
  const int tid = threadIdx.x;

  if (tid < 24) {
    if (tid < 2) {                       // f_start: randint(kf1,(64,2),0,102)
      uint32_t ka, kb; jax_subkey42(0, ka, kb);
      s_fs[tid] = (int)jax_randint0(ka, kb, (uint32_t)(b * 2 + tid), 102u, 52u);
    } else if (tid < 4) {                // f_w: randint(kf2,(64,2),0,28)
      int m = tid - 2;
      uint32_t ka, kb; jax_subkey42(1, ka, kb);
      s_fw[m] = (int)jax_randint0(ka, kb, (uint32_t)(b * 2 + m), 28u, 4u);
    } else if (tid < 14) {               // t_start: floor(uniform(kt1,(64,10)) * max_start)
      int m = tid - 4;
      uint32_t ka, kb; jax_subkey42(2, ka, kb);
      uint32_t bits = jax_bits32(ka, kb, (uint32_t)(b * 10 + m));
      float u = __uint_as_float((bits >> 9) | 0x3F800000u) - 1.0f;  // [0,1)
      int ms = len[b] - 99; if (ms < 1) ms = 1;                     // max(length-TW+1, 1)
      s_ts[m] = (int)floorf(u * (float)ms);
    } else {                             // t_w: randint(kt2,(64,10),0,101)
      int m = tid - 14;
      uint32_t ka, kb; jax_subkey42(3, ka, kb);
      s_tw[m] = (int)jax_randint0(ka, kb, (uint32_t)(b * 10 + m), 101u, 68u);
    }
  }
  __syncthreads();

  const int t4 = blockIdx.x * 256 + tid;   // float4 index within row
  if (t4 >= NT4) return;                   // no further barriers -> safe early-exit
  const int t0 = t4 * 4;

  // per-component time-keep multiplier (0.0 where any time mask hits)
  float m0 = 1.f, m1 = 1.f, m2 = 1.f, m3 = 1.f;
#pragma unroll
  for (int m = 0; m < 10; ++m) {
    int ts = s_ts[m], te = ts + s_tw[m];
    if (t0     >= ts && t0     < te) m0 = 0.f;
    if (t0 + 1 >= ts && t0 + 1 < te) m1 = 0.f;
    if (t0 + 2 >= ts && t0 + 2 < te) m2 = 0.f;
    if (t0 + 3 >= ts && t0 + 3 < te) m3 = 0.f;
  }

  const int d0 = blockIdx.z * 16;
  // freq-hit bitmask for this block's 16 d-rows (block-uniform)
  const int fs0 = s_fs[0], fe0 = fs0 + s_fw[0];
  const int fs1 = s_fs[1], fe1 = fs1 + s_fw[1];
  uint32_t fmask = 0;
#pragma unroll
  for (int u = 0; u < 16; ++u) {
    int d = d0 + u;
    bool fh = (d >= fs0 && d < fe0) || (d >= fs1 && d < fe1);
    fmask |= (uint32_t)fh << u;
  }

  const f32x4* __restrict__ x4 = reinterpret_cast<const f32x4*>(x);
  f32x4* __restrict__ o4       = reinterpret_cast<f32x4*>(out);
  int64_t idx = (int64_t)(b * DD + d0) * NT4 + t4;
  const f32x4 z4 = (f32x4){0.f, 0.f, 0.f, 0.f};
  const f32x4 mm = (f32x4){m0, m1, m2, m3};

  // 4 groups of 4 rows: batch 4 loads, then 4 nontemporal stores (deep VMEM queue)
#pragma unroll
  for (int g = 0; g < 4; ++g) {
    f32x4 v0 = z4, v1 = z4, v2 = z4, v3 = z4;
    const uint32_t fm = (fmask >> (g * 4)) & 0xF;
    if (!(fm & 1u)) v0 = x4[idx + 0 * NT4];
    if (!(fm & 2u)) v1 = x4[idx + 1 * NT4];
    if (!(fm & 4u)) v2 = x4[idx + 2 * NT4];
    if (!(fm & 8u)) v3 = x4[idx + 3 * NT4];
    v0 *= mm; v1 *= mm; v2 *= mm; v3 *= mm;
    __builtin_nontemporal_store(v0, &o4[idx + 0 * NT4]);
    __builtin_nontemporal_store(v1, &o4[idx + 1 * NT4]);
    __builtin_nontemporal_store(v2, &o4[idx + 2 * NT4]);
    __builtin_nontemporal_store(v3, &o4[idx + 3 * NT4]);
    idx += 4 * NT4;
  }
}

extern "C" void kernel_launch(void* const* d_in, const int* in_sizes, int n_in,
                              void* d_out, int out_size, void* d_ws, size_t ws_size,
                              hipStream_t stream) {
  (void)in_sizes; (void)n_in; (void)d_ws; (void)ws_size; (void)out_size;
  const float* x  = (const float*)d_in[0];
  const int* len  = (const int*)d_in[1];
  float* out      = (float*)d_out;
  dim3 grid(4 /* ceil(NT4/256) */, BB, DD / 16);
  dim3 block(256);
  hipLaunchKernelGGL(specaug_kernel, grid, block, 0, stream, x, len, out);
}